// Round 11
// baseline (371.256 us; speedup 1.0000x reference)
//
#include <hip/hip_runtime.h>
#include <hip/hip_bf16.h>
#include <stdint.h>

typedef __attribute__((ext_vector_type(8))) __bf16 bf16x8;
typedef __attribute__((ext_vector_type(4))) float f32x4;

#define GLOAD_LDS16(gp, lp) __builtin_amdgcn_global_load_lds( \
    (const __attribute__((address_space(1))) void*)(gp),      \
    (__attribute__((address_space(3))) void*)(lp), 16, 0, 0)

__device__ __forceinline__ uint16_t f2bf_rne(float f) {
  uint32_t u = __float_as_uint(f);
  u += 0x7FFFu + ((u >> 16) & 1u);
  return (uint16_t)(u >> 16);
}

// ---------------- f32 -> bf16 conversion for z only (50 MB traffic) ---------
__global__ __launch_bounds__(256) void cvt_z(
    const float* __restrict__ src, uint16_t* __restrict__ dst) {
  int i = blockIdx.x * 256 + threadIdx.x;
  const float4* s4 = (const float4*)src;
  float4 a = s4[2 * i], b = s4[2 * i + 1];
  union { uint16_t u[8]; uint4 v; } o;
  o.u[0] = f2bf_rne(a.x); o.u[1] = f2bf_rne(a.y);
  o.u[2] = f2bf_rne(a.z); o.u[3] = f2bf_rne(a.w);
  o.u[4] = f2bf_rne(b.x); o.u[5] = f2bf_rne(b.y);
  o.u[6] = f2bf_rne(b.z); o.u[7] = f2bf_rne(b.w);
  ((uint4*)dst)[i] = o.v;
}

// ---------------- bf16 GEMM, 256x256 tile, 16 waves, ring-4 BK=32 -----------
// R11 = R6 dataflow + B staged from f32 W (reg->cvt->swizzled ds_write, R10's
// functionally-verified path) with CORRECTED pipeline depth: 3 B reg buffers,
// iter j loads B(j+3), packs B(j+1) after vmcnt(6) = 2-iter HBM slack (R10's
// vmcnt(3) = 1-iter slack was the regression; R8 same lesson).
// Ledger @ iter j: issue B(j+3)->buf(j%3) (2 ops) + A(j+3) gload (1 op);
// vmcnt(6) => all ops <= iter j-2 complete => B(j+1) regs ready ✓, A(j+1) LDS
// ready ✓ (read next iter). Pack B(j+1) -> slot (j+1)&3 (B region last read
// iter j-3 ✓). Buffers: load j%3, pack (j+1)%3, idle (j+2)%3 — disjoint ✓.
#define PH_BAR() do { asm volatile("" ::: "memory");            \
                      __builtin_amdgcn_s_barrier();             \
                      asm volatile("" ::: "memory"); } while (0)

#define PACK_WRITE(KT, WA0, WA1)                                               \
  do {                                                                         \
    uint4 wv_;                                                                 \
    wv_.x = (uint32_t)f2bf_rne(WA0[0]) | ((uint32_t)f2bf_rne(WA0[1]) << 16);   \
    wv_.y = (uint32_t)f2bf_rne(WA0[2]) | ((uint32_t)f2bf_rne(WA0[3]) << 16);   \
    wv_.z = (uint32_t)f2bf_rne(WA1[0]) | ((uint32_t)f2bf_rne(WA1[1]) << 16);   \
    wv_.w = (uint32_t)f2bf_rne(WA1[2]) | ((uint32_t)f2bf_rne(WA1[3]) << 16);   \
    *(uint4*)(lds + (((KT) + 1) & 3) * 32768 + 16384 + bwoff) = wv_;           \
  } while (0)

#define STEP(KT, WB0, WB1, LB0, LB1, DO_A, DO_BL, DO_PK, VMN)                  \
  do {                                                                         \
    const char* Sb_ = lds + ((KT) & 3) * 32768;                                \
    bf16x8 aa[4], bb[4];                                                       \
    _Pragma("unroll")                                                          \
    for (int n_ = 0; n_ < 4; ++n_)                                             \
      bb[n_] = *(const bf16x8*)(Sb_ + 16384 + boff + n_ * 1024);               \
    _Pragma("unroll")                                                          \
    for (int m_ = 0; m_ < 4; ++m_)                                             \
      aa[m_] = *(const bf16x8*)(Sb_ + aoff + m_ * 1024);                       \
    if (DO_BL) {                                                               \
      LB0 = *(const f32x4*)(bsrc + (size_t)((KT) + 3) * 32);                   \
      LB1 = *(const f32x4*)(bsrc + (size_t)((KT) + 3) * 32 + 4);               \
    }                                                                          \
    if (DO_A)                                                                  \
      GLOAD_LDS16(aptr + (size_t)((KT) + 3) * 32,                              \
                  lds + (((KT) + 3) & 3) * 32768 + t16);                       \
    __builtin_amdgcn_s_setprio(1);                                             \
    _Pragma("unroll")                                                          \
    for (int m_ = 0; m_ < 4; ++m_)                                             \
      _Pragma("unroll")                                                        \
      for (int n_ = 0; n_ < 4; ++n_)                                           \
        acc[m_][n_] = __builtin_amdgcn_mfma_f32_16x16x32_bf16(                 \
            aa[m_], bb[n_], acc[m_][n_], 0, 0, 0);                             \
    __builtin_amdgcn_s_setprio(0);                                             \
    asm volatile("s_waitcnt vmcnt(" #VMN ")" ::: "memory");                    \
    if (DO_PK) PACK_WRITE(KT, WB0, WB1);                                       \
    asm volatile("s_waitcnt lgkmcnt(0)" ::: "memory");                         \
    PH_BAR();                                                                  \
  } while (0)

__global__ __launch_bounds__(1024, 4) void gemm_qk16(
    const uint16_t* __restrict__ A,
    const float* __restrict__ Wq, const float* __restrict__ Wk,
    uint16_t* __restrict__ Cq, uint16_t* __restrict__ Ck) {
  extern __shared__ char lds[];  // 131072: 4 ring slots x (A 16K + B 16K)

  // bijective supertile: xcd = gid&7 -> (tm half, tn quarter); 32 blocks/XCD
  const int gid = blockIdx.x;
  const int xcd = gid & 7;
  const int idx = gid >> 3;          // 0..31
  const int which = idx & 1;
  const int r = idx >> 1;            // 0..15
  const int tm = (xcd & 1) * 4 + (r & 3);
  const int tn = (xcd >> 1) * 4 + (r >> 2);

  const float* Bmat = which ? Wk : Wq;
  uint16_t* C = which ? Ck : Cq;
  const int m0 = tm * 256, n0 = tn * 256;

  const int t = threadIdx.x;
  const int lane = t & 63;
  const int w = t >> 6;              // 0..15
  const int wm = w >> 2, wn = w & 3; // 4x4 wave grid, each 64x64 output
  const int t16 = t * 16;

  // A staging (gload_lds): thread t covers row t>>2, k-granule t&3,
  // pre-swizzled source granule (involution with read-side sl)
  const int gsw = (((t & 3) ^ ((t >> 3) & 3)) * 8);
  const uint16_t* aptr = A + (size_t)(m0 + (t >> 2)) * 4096 + gsw;

  // B staging (reg + cvt + ds_write): f32 source, PLAIN k order; swizzle
  // applied on the ds_write address (R10-verified mapping).
  const float* bsrc = Bmat + (size_t)(n0 + (t >> 2)) * 4096 + (t & 3) * 8;
  const int bwoff = (t >> 2) * 64 + (((t & 3) ^ ((t >> 3) & 3)) * 16);

  // ds_read byte offsets (XOR involution on the read side)
  const int sl = ((lane >> 4) ^ ((lane & 15) >> 1)) & 3;
  const int aoff = (wm * 64 + (lane & 15)) * 64 + sl * 16;
  const int boff = (wn * 64 + (lane & 15)) * 64 + sl * 16;

  f32x4 acc[4][4] = {};
  f32x4 b0a, b0b, b1a, b1b, b2a, b2b;  // 3 B reg buffers (rotation)

  // prologue: A tiles 0,1,2 -> slots 0,1,2; B tiles 0,1,2 -> buf0,1,2;
  // pack B0 -> slot 0.
#pragma unroll
  for (int p = 0; p < 3; ++p)
    GLOAD_LDS16(aptr + (size_t)p * 32, lds + p * 32768 + t16);
  b0a = *(const f32x4*)(bsrc);
  b0b = *(const f32x4*)(bsrc + 4);
  b1a = *(const f32x4*)(bsrc + 32);
  b1b = *(const f32x4*)(bsrc + 36);
  b2a = *(const f32x4*)(bsrc + 64);
  b2b = *(const f32x4*)(bsrc + 68);
  asm volatile("s_waitcnt vmcnt(0)" ::: "memory");
  {
    uint4 wv_;
    wv_.x = (uint32_t)f2bf_rne(b0a[0]) | ((uint32_t)f2bf_rne(b0a[1]) << 16);
    wv_.y = (uint32_t)f2bf_rne(b0a[2]) | ((uint32_t)f2bf_rne(b0a[3]) << 16);
    wv_.z = (uint32_t)f2bf_rne(b0b[0]) | ((uint32_t)f2bf_rne(b0b[1]) << 16);
    wv_.w = (uint32_t)f2bf_rne(b0b[2]) | ((uint32_t)f2bf_rne(b0b[3]) << 16);
    *(uint4*)(lds + 16384 + bwoff) = wv_;  // B tile 0 -> slot 0
  }
  asm volatile("s_waitcnt lgkmcnt(0)" ::: "memory");
  PH_BAR();

  // main: j = 0..122 in 41 triples (all load B(j+3)<=125, stage A(j+3)<=125)
  for (int it = 0; it < 41; ++it) {
    const int kt0 = it * 3;
    STEP(kt0 + 0, b1a, b1b, b0a, b0b, 1, 1, 1, 6);  // pack B(j+1)=buf1, load->buf0
    STEP(kt0 + 1, b2a, b2b, b1a, b1b, 1, 1, 1, 6);
    STEP(kt0 + 2, b0a, b0b, b2a, b2b, 1, 1, 1, 6);
  }
  // tail: j = 123..127
  STEP(123, b1a, b1b, b0a, b0b, 1, 1, 1, 6);  // loads B126, stages A126
  STEP(124, b2a, b2b, b1a, b1b, 1, 1, 1, 6);  // loads B127, stages A127
  STEP(125, b0a, b0b, b2a, b2b, 0, 0, 1, 3);  // packs B126
  STEP(126, b1a, b1b, b0a, b0b, 0, 0, 1, 0);  // packs B127
  {  // j = 127: pure compute
    const char* Sb_ = lds + 3 * 32768;
    bf16x8 aa[4], bb[4];
#pragma unroll
    for (int n_ = 0; n_ < 4; ++n_)
      bb[n_] = *(const bf16x8*)(Sb_ + 16384 + boff + n_ * 1024);
#pragma unroll
    for (int m_ = 0; m_ < 4; ++m_)
      aa[m_] = *(const bf16x8*)(Sb_ + aoff + m_ * 1024);
#pragma unroll
    for (int m_ = 0; m_ < 4; ++m_)
#pragma unroll
      for (int n_ = 0; n_ < 4; ++n_)
        acc[m_][n_] = __builtin_amdgcn_mfma_f32_16x16x32_bf16(
            aa[m_], bb[n_], acc[m_][n_], 0, 0, 0);
  }

  // epilogue: C/D layout col=lane&15, row=(lane>>4)*4+j ; store bf16
  const int colb = n0 + wn * 64 + (lane & 15);
  const int rowb = m0 + wm * 64 + (lane >> 4) * 4;
#pragma unroll
  for (int m_ = 0; m_ < 4; ++m_)
#pragma unroll
    for (int n_ = 0; n_ < 4; ++n_)
#pragma unroll
      for (int j = 0; j < 4; ++j)
        C[(size_t)(rowb + m_ * 16 + j) * 4096 + colb + n_ * 16] =
            f2bf_rne(acc[m_][n_][j]);
}

// ---------------- MFMA scores + softmax -> attn[256][64][64] f32 ------------
__device__ __forceinline__ bf16x8 load_frag_rot(const uint16_t* buf,
                                                int ij, int thb) {
  union { uint16_t u[8]; bf16x8 v; } r;
#pragma unroll
  for (int e = 0; e < 8; ++e) {
    const int th = thb + e;
    const int rot = (th + 2 * (th >> 3)) & 7;
    const int irot = (ij + rot * 8) & 63;
    r.u[e] = buf[th * 64 + irot];
  }
  return r.v;
}

__global__ __launch_bounds__(256) void attn_scores_mfma(
    const uint16_t* __restrict__ Qb, const uint16_t* __restrict__ Kb,
    float* __restrict__ attn) {
  const int n = blockIdx.x;
  __shared__ uint16_t q_l[2][4096];
  __shared__ uint16_t k_l[2][4096];
  __shared__ float scores_l[64 * 68];

  const int t = threadIdx.x;
  const int lane = t & 63;
  const int w = t >> 6;
  const int i0w = (w >> 1) * 32, j0w = (w & 1) * 32;

  const uint16_t* Qn = Qb + (size_t)n * 32768;
  const uint16_t* Kn = Kb + (size_t)n * 32768;

  const int g1 = t, g2 = t + 256;
  const int th1 = g1 >> 3, th2 = g2 >> 3;
  const int s1 = (((g1 & 7) - ((th1 + 2 * (th1 >> 3)) & 7)) & 7);
  const int s2 = (((g2 & 7) - ((th2 + 2 * (th2 >> 3)) & 7)) & 7);
  const size_t so1 = (size_t)th1 * 64 + s1 * 8;
  const size_t so2 = (size_t)th2 * 64 + s2 * 8;

#define STAGE_CH(bf, cm)                                                    \
  do {                                                                      \
    const size_t co_ = (size_t)(cm) * 4096;                                 \
    GLOAD_LDS16(Qn + co_ + so1, (char*)&q_l[bf][0] + g1 * 16);              \
    GLOAD_LDS16(Qn + co_ + so2, (char*)&q_l[bf][0] + g2 * 16);              \
    GLOAD_LDS16(Kn + co_ + so1, (char*)&k_l[bf][0] + g1 * 16);              \
    GLOAD_LDS16(Kn + co_ + so2, (char*)&k_l[bf][0] + g2 * 16);              \
  } while (0)

  f32x4 acc[2][2] = {};

  STAGE_CH(0, 0);
  asm volatile("s_waitcnt vmcnt(0)" ::: "memory");
  __syncthreads();

  for (int cm = 0; cm < 8; ++cm) {
    const int bf = cm & 1;
    if (cm < 7) STAGE_CH(bf ^ 1, cm + 1);
#pragma unroll
    for (int ks = 0; ks < 2; ++ks) {
      const int thb = ks * 32 + (lane >> 4) * 8;
      bf16x8 aa0 = load_frag_rot(&q_l[bf][0], i0w + (lane & 15), thb);
      bf16x8 aa1 = load_frag_rot(&q_l[bf][0], i0w + 16 + (lane & 15), thb);
      bf16x8 bb0 = load_frag_rot(&k_l[bf][0], j0w + (lane & 15), thb);
      bf16x8 bb1 = load_frag_rot(&k_l[bf][0], j0w + 16 + (lane & 15), thb);
      acc[0][0] = __builtin_amdgcn_mfma_f32_16x16x32_bf16(aa0, bb0, acc[0][0], 0, 0, 0);
      acc[0][1] = __builtin_amdgcn_mfma_f32_16x16x32_bf16(aa0, bb1, acc[0][1], 0, 0, 0);
      acc[1][0] = __builtin_amdgcn_mfma_f32_16x16x32_bf16(aa1, bb0, acc[1][0], 0, 0, 0);
      acc[1][1] = __builtin_amdgcn_mfma_f32_16x16x32_bf16(aa1, bb1, acc[1][1], 0, 0, 0);
    }
    asm volatile("s_waitcnt vmcnt(0)" ::: "memory");
    __syncthreads();
  }
#undef STAGE_CH

#pragma unroll
  for (int fi = 0; fi < 2; ++fi)
#pragma unroll
    for (int fj = 0; fj < 2; ++fj)
#pragma unroll
      for (int jr = 0; jr < 4; ++jr) {
        const int i = i0w + fi * 16 + (lane >> 4) * 4 + jr;
        const int j = j0w + fj * 16 + (lane & 15);
        scores_l[i * 68 + j] = acc[fi][fj][jr];
      }
  __syncthreads();

  {
    const int i = t >> 2, jg = t & 3;
    float pv[16];
    *(float4*)(pv + 0)  = *(const float4*)&scores_l[i * 68 + jg * 16 + 0];
    *(float4*)(pv + 4)  = *(const float4*)&scores_l[i * 68 + jg * 16 + 4];
    *(float4*)(pv + 8)  = *(const float4*)&scores_l[i * 68 + jg * 16 + 8];
    *(float4*)(pv + 12) = *(const float4*)&scores_l[i * 68 + jg * 16 + 12];
    float m = pv[0];
#pragma unroll
    for (int q = 1; q < 16; ++q) m = fmaxf(m, pv[q]);
    m = fmaxf(m, __shfl_xor(m, 1, 64));
    m = fmaxf(m, __shfl_xor(m, 2, 64));
    const float sc = 0.044194173824159216f * 1.4426950408889634f;
    float e[16];
    float ssum = 0.f;
#pragma unroll
    for (int q = 0; q < 16; ++q) {
      e[q] = exp2f((pv[q] - m) * sc);
      ssum += e[q];
    }
    ssum += __shfl_xor(ssum, 1, 64);
    ssum += __shfl_xor(ssum, 2, 64);
    const float inv = 1.0f / ssum;
    float ov[16];
#pragma unroll
    for (int q = 0; q < 16; ++q) ov[q] = e[q] * inv;
    float* dst = attn + (size_t)n * 4096 + i * 64 + jg * 16;
    *(float4*)(dst + 0)  = *(float4*)(ov + 0);
    *(float4*)(dst + 4)  = *(float4*)(ov + 4);
    *(float4*)(dst + 8)  = *(float4*)(ov + 8);
    *(float4*)(dst + 12) = *(float4*)(ov + 12);
  }
}

// ---------------- V = x-slab * Wv^T ; context = V @ attn ; leaky; scatter ----
__global__ __launch_bounds__(256) void ctx_kernel(
    const float* __restrict__ x, const float* __restrict__ Wv,
    const float* __restrict__ attn, float* __restrict__ out) {
  const int n = blockIdx.x >> 3, ut = blockIdx.x & 7;
  const int b = n >> 3, g = n & 7;
  const int u0 = ut * 64;
  __shared__ float attn_l[64 * 64];
  __shared__ float wv_l[64 * 64];
  __shared__ float x_l[64 * 64];
  __shared__ float v_l[64 * 64];
  const int t = threadIdx.x;

#pragma unroll
  for (int r = 0; r < 4; ++r) {
    ((float4*)attn_l)[r * 256 + t] =
        ((const float4*)(attn + (size_t)n * 4096))[r * 256 + t];
    ((float4*)wv_l)[r * 256 + t] = ((const float4*)Wv)[r * 256 + t];
  }
  {
    const float* xbase = x + (size_t)b * 262144 + (size_t)g * 512 + u0;
    const int ul4 = (t & 15) * 4;
    const int cc0 = t >> 4;
#pragma unroll
    for (int r = 0; r < 4; ++r) {
      int cc = cc0 + r * 16;
      *(float4*)&x_l[cc * 64 + ul4] = *(const float4*)&xbase[(size_t)cc * 4096 + ul4];
    }
  }
  __syncthreads();
  {
    const int ul = t & 63, e0 = t >> 6;
    float vacc[16];
#pragma unroll
    for (int ee = 0; ee < 16; ++ee) vacc[ee] = 0.f;
    for (int cc = 0; cc < 64; ++cc) {
      float xv = x_l[cc * 64 + ul];
#pragma unroll
      for (int ee = 0; ee < 16; ++ee)
        vacc[ee] += xv * wv_l[(e0 + 4 * ee) * 64 + cc];
    }
#pragma unroll
    for (int ee = 0; ee < 16; ++ee) v_l[(e0 + 4 * ee) * 64 + ul] = vacc[ee];
  }
  __syncthreads();
  {
    const int ul = t & 63, j0 = t >> 6;
    float cacc[16];
#pragma unroll
    for (int jj = 0; jj < 16; ++jj) cacc[jj] = 0.f;
    for (int c = 0; c < 64; ++c) {
      float vv = v_l[c * 64 + ul];
#pragma unroll
      for (int jj = 0; jj < 16; ++jj)
        cacc[jj] += vv * attn_l[c * 64 + j0 + 4 * jj];
    }
    float* ob = out + (size_t)b * 262144 + (size_t)g * 8 * 4096;
#pragma unroll
    for (int jj = 0; jj < 16; ++jj) {
      int j = j0 + 4 * jj;
      float v = cacc[jj];
      v = v > 0.f ? v : 0.2f * v;
      ob[(size_t)(j >> 3) * 4096 + (size_t)(j & 7) * 512 + u0 + ul] = v;
    }
  }
}

extern "C" void kernel_launch(void* const* d_in, const int* in_sizes, int n_in,
                              void* d_out, int out_size, void* d_ws, size_t ws_size,
                              hipStream_t stream) {
  const float* z  = (const float*)d_in[0];
  const float* x  = (const float*)d_in[1];
  const float* Wq = (const float*)d_in[2];
  const float* Wk = (const float*)d_in[3];
  const float* Wv = (const float*)d_in[4];
  float* out = (float*)d_out;

  char* ws = (char*)d_ws;
  uint16_t* zb   = (uint16_t*)(ws);                  // 16 MB bf16 z
  uint16_t* qbo  = (uint16_t*)(ws + 16777216);       // 16 MB bf16 Q
  uint16_t* kbo  = (uint16_t*)(ws + 33554432);       // 16 MB bf16 K
  float*    attn = (float*)(ws + 50331648);          // 4 MB f32

  cvt_z<<<4096, 256, 0, stream>>>(z, zb);

  (void)hipFuncSetAttribute((const void*)gemm_qk16,
                            hipFuncAttributeMaxDynamicSharedMemorySize, 131072);
  gemm_qk16<<<256, 1024, 131072, stream>>>(zb, Wq, Wk, qbo, kbo);

  attn_scores_mfma<<<256, 256, 0, stream>>>(qbo, kbo, attn);
  ctx_kernel<<<2048, 256, 0, stream>>>(x, Wv, attn, out);
}

// Round 12
// 360.485 us; speedup vs baseline: 1.0299x; 1.0299x over previous
//
#include <hip/hip_runtime.h>
#include <hip/hip_bf16.h>
#include <stdint.h>

typedef __attribute__((ext_vector_type(8))) __bf16 bf16x8;
typedef __attribute__((ext_vector_type(4))) float f32x4;

#define GLOAD_LDS16(gp, lp) __builtin_amdgcn_global_load_lds( \
    (const __attribute__((address_space(1))) void*)(gp),      \
    (__attribute__((address_space(3))) void*)(lp), 16, 0, 0)

__device__ __forceinline__ uint16_t f2bf_rne(float f) {
  uint32_t u = __float_as_uint(f);
  u += 0x7FFFu + ((u >> 16) & 1u);
  return (uint16_t)(u >> 16);
}

// ---------------- f32 -> bf16 conversion for z only (50 MB traffic) ---------
__global__ __launch_bounds__(256) void cvt_z(
    const float* __restrict__ src, uint16_t* __restrict__ dst) {
  int i = blockIdx.x * 256 + threadIdx.x;
  const float4* s4 = (const float4*)src;
  float4 a = s4[2 * i], b = s4[2 * i + 1];
  union { uint16_t u[8]; uint4 v; } o;
  o.u[0] = f2bf_rne(a.x); o.u[1] = f2bf_rne(a.y);
  o.u[2] = f2bf_rne(a.z); o.u[3] = f2bf_rne(a.w);
  o.u[4] = f2bf_rne(b.x); o.u[5] = f2bf_rne(b.y);
  o.u[6] = f2bf_rne(b.z); o.u[7] = f2bf_rne(b.w);
  ((uint4*)dst)[i] = o.v;
}

// ---------------- bf16 GEMM, 256x256 tile, 16 waves, ring-4 BK=32 -----------
// R12 = R11 with __launch_bounds__(1024, 3). R10/R11's regression was
// REGISTER SPILL, not pipeline depth: at (1024,4) the unified budget is 128
// (acc AGPR 64 + arch ~78 = 142 > 128 -> ~14 spilled regs -> WRITE_SIZE
// 283 MB of scratch). (1024,3) gives budget 170 >= 142 -> no spill, 3
// waves/SIMD. Dataflow ledger identical to R11 (verified correct, absmax ok):
// iter j: read tile j frags; load B(j+3)->buf(j%3); gload A(j+3); MFMA;
// vmcnt(6)=2-iter slack; pack B(j+1)->slot (j+1)&3; lgkmcnt(0); barrier.
#define PH_BAR() do { asm volatile("" ::: "memory");            \
                      __builtin_amdgcn_s_barrier();             \
                      asm volatile("" ::: "memory"); } while (0)

#define PACK_WRITE(KT, WA0, WA1)                                               \
  do {                                                                         \
    uint4 wv_;                                                                 \
    wv_.x = (uint32_t)f2bf_rne(WA0[0]) | ((uint32_t)f2bf_rne(WA0[1]) << 16);   \
    wv_.y = (uint32_t)f2bf_rne(WA0[2]) | ((uint32_t)f2bf_rne(WA0[3]) << 16);   \
    wv_.z = (uint32_t)f2bf_rne(WA1[0]) | ((uint32_t)f2bf_rne(WA1[1]) << 16);   \
    wv_.w = (uint32_t)f2bf_rne(WA1[2]) | ((uint32_t)f2bf_rne(WA1[3]) << 16);   \
    *(uint4*)(lds + (((KT) + 1) & 3) * 32768 + 16384 + bwoff) = wv_;           \
  } while (0)

#define STEP(KT, WB0, WB1, LB0, LB1, DO_A, DO_BL, DO_PK, VMN)                  \
  do {                                                                         \
    const char* Sb_ = lds + ((KT) & 3) * 32768;                                \
    bf16x8 aa[4], bb[4];                                                       \
    _Pragma("unroll")                                                          \
    for (int n_ = 0; n_ < 4; ++n_)                                             \
      bb[n_] = *(const bf16x8*)(Sb_ + 16384 + boff + n_ * 1024);               \
    _Pragma("unroll")                                                          \
    for (int m_ = 0; m_ < 4; ++m_)                                             \
      aa[m_] = *(const bf16x8*)(Sb_ + aoff + m_ * 1024);                       \
    if (DO_BL) {                                                               \
      LB0 = *(const f32x4*)(bsrc + (size_t)((KT) + 3) * 32);                   \
      LB1 = *(const f32x4*)(bsrc + (size_t)((KT) + 3) * 32 + 4);               \
    }                                                                          \
    if (DO_A)                                                                  \
      GLOAD_LDS16(aptr + (size_t)((KT) + 3) * 32,                              \
                  lds + (((KT) + 3) & 3) * 32768 + t16);                       \
    __builtin_amdgcn_s_setprio(1);                                             \
    _Pragma("unroll")                                                          \
    for (int m_ = 0; m_ < 4; ++m_)                                             \
      _Pragma("unroll")                                                        \
      for (int n_ = 0; n_ < 4; ++n_)                                           \
        acc[m_][n_] = __builtin_amdgcn_mfma_f32_16x16x32_bf16(                 \
            aa[m_], bb[n_], acc[m_][n_], 0, 0, 0);                             \
    __builtin_amdgcn_s_setprio(0);                                             \
    asm volatile("s_waitcnt vmcnt(" #VMN ")" ::: "memory");                    \
    if (DO_PK) PACK_WRITE(KT, WB0, WB1);                                       \
    asm volatile("s_waitcnt lgkmcnt(0)" ::: "memory");                         \
    PH_BAR();                                                                  \
  } while (0)

__global__ __launch_bounds__(1024, 3) void gemm_qk16(
    const uint16_t* __restrict__ A,
    const float* __restrict__ Wq, const float* __restrict__ Wk,
    uint16_t* __restrict__ Cq, uint16_t* __restrict__ Ck) {
  extern __shared__ char lds[];  // 131072: 4 ring slots x (A 16K + B 16K)

  // bijective supertile: xcd = gid&7 -> (tm half, tn quarter); 32 blocks/XCD
  const int gid = blockIdx.x;
  const int xcd = gid & 7;
  const int idx = gid >> 3;          // 0..31
  const int which = idx & 1;
  const int r = idx >> 1;            // 0..15
  const int tm = (xcd & 1) * 4 + (r & 3);
  const int tn = (xcd >> 1) * 4 + (r >> 2);

  const float* Bmat = which ? Wk : Wq;
  uint16_t* C = which ? Ck : Cq;
  const int m0 = tm * 256, n0 = tn * 256;

  const int t = threadIdx.x;
  const int lane = t & 63;
  const int w = t >> 6;              // 0..15
  const int wm = w >> 2, wn = w & 3; // 4x4 wave grid, each 64x64 output
  const int t16 = t * 16;

  // A staging (gload_lds): thread t covers row t>>2, k-granule t&3,
  // pre-swizzled source granule (involution with read-side sl)
  const int gsw = (((t & 3) ^ ((t >> 3) & 3)) * 8);
  const uint16_t* aptr = A + (size_t)(m0 + (t >> 2)) * 4096 + gsw;

  // B staging (reg + cvt + ds_write): f32 source, PLAIN k order; swizzle
  // applied on the ds_write address (R10/R11-verified mapping).
  const float* bsrc = Bmat + (size_t)(n0 + (t >> 2)) * 4096 + (t & 3) * 8;
  const int bwoff = (t >> 2) * 64 + (((t & 3) ^ ((t >> 3) & 3)) * 16);

  // ds_read byte offsets (XOR involution on the read side)
  const int sl = ((lane >> 4) ^ ((lane & 15) >> 1)) & 3;
  const int aoff = (wm * 64 + (lane & 15)) * 64 + sl * 16;
  const int boff = (wn * 64 + (lane & 15)) * 64 + sl * 16;

  f32x4 acc[4][4] = {};
  f32x4 b0a, b0b, b1a, b1b, b2a, b2b;  // 3 B reg buffers (rotation)

  // prologue: A tiles 0,1,2 -> slots 0,1,2; B tiles 0,1,2 -> buf0,1,2;
  // pack B0 -> slot 0.
#pragma unroll
  for (int p = 0; p < 3; ++p)
    GLOAD_LDS16(aptr + (size_t)p * 32, lds + p * 32768 + t16);
  b0a = *(const f32x4*)(bsrc);
  b0b = *(const f32x4*)(bsrc + 4);
  b1a = *(const f32x4*)(bsrc + 32);
  b1b = *(const f32x4*)(bsrc + 36);
  b2a = *(const f32x4*)(bsrc + 64);
  b2b = *(const f32x4*)(bsrc + 68);
  asm volatile("s_waitcnt vmcnt(0)" ::: "memory");
  {
    uint4 wv_;
    wv_.x = (uint32_t)f2bf_rne(b0a[0]) | ((uint32_t)f2bf_rne(b0a[1]) << 16);
    wv_.y = (uint32_t)f2bf_rne(b0a[2]) | ((uint32_t)f2bf_rne(b0a[3]) << 16);
    wv_.z = (uint32_t)f2bf_rne(b0b[0]) | ((uint32_t)f2bf_rne(b0b[1]) << 16);
    wv_.w = (uint32_t)f2bf_rne(b0b[2]) | ((uint32_t)f2bf_rne(b0b[3]) << 16);
    *(uint4*)(lds + 16384 + bwoff) = wv_;  // B tile 0 -> slot 0
  }
  asm volatile("s_waitcnt lgkmcnt(0)" ::: "memory");
  PH_BAR();

  // main: j = 0..122 in 41 triples (all load B(j+3)<=125, stage A(j+3)<=125)
  for (int it = 0; it < 41; ++it) {
    const int kt0 = it * 3;
    STEP(kt0 + 0, b1a, b1b, b0a, b0b, 1, 1, 1, 6);  // pack B(j+1)=buf1, load->buf0
    STEP(kt0 + 1, b2a, b2b, b1a, b1b, 1, 1, 1, 6);
    STEP(kt0 + 2, b0a, b0b, b2a, b2b, 1, 1, 1, 6);
  }
  // tail: j = 123..127
  STEP(123, b1a, b1b, b0a, b0b, 1, 1, 1, 6);  // loads B126, stages A126
  STEP(124, b2a, b2b, b1a, b1b, 1, 1, 1, 6);  // loads B127, stages A127
  STEP(125, b0a, b0b, b2a, b2b, 0, 0, 1, 3);  // packs B126
  STEP(126, b1a, b1b, b0a, b0b, 0, 0, 1, 0);  // packs B127
  {  // j = 127: pure compute
    const char* Sb_ = lds + 3 * 32768;
    bf16x8 aa[4], bb[4];
#pragma unroll
    for (int n_ = 0; n_ < 4; ++n_)
      bb[n_] = *(const bf16x8*)(Sb_ + 16384 + boff + n_ * 1024);
#pragma unroll
    for (int m_ = 0; m_ < 4; ++m_)
      aa[m_] = *(const bf16x8*)(Sb_ + aoff + m_ * 1024);
#pragma unroll
    for (int m_ = 0; m_ < 4; ++m_)
#pragma unroll
      for (int n_ = 0; n_ < 4; ++n_)
        acc[m_][n_] = __builtin_amdgcn_mfma_f32_16x16x32_bf16(
            aa[m_], bb[n_], acc[m_][n_], 0, 0, 0);
  }

  // epilogue: C/D layout col=lane&15, row=(lane>>4)*4+j ; store bf16
  const int colb = n0 + wn * 64 + (lane & 15);
  const int rowb = m0 + wm * 64 + (lane >> 4) * 4;
#pragma unroll
  for (int m_ = 0; m_ < 4; ++m_)
#pragma unroll
    for (int n_ = 0; n_ < 4; ++n_)
#pragma unroll
      for (int j = 0; j < 4; ++j)
        C[(size_t)(rowb + m_ * 16 + j) * 4096 + colb + n_ * 16] =
            f2bf_rne(acc[m_][n_][j]);
}

// ---------------- MFMA scores + softmax -> attn[256][64][64] f32 ------------
__device__ __forceinline__ bf16x8 load_frag_rot(const uint16_t* buf,
                                                int ij, int thb) {
  union { uint16_t u[8]; bf16x8 v; } r;
#pragma unroll
  for (int e = 0; e < 8; ++e) {
    const int th = thb + e;
    const int rot = (th + 2 * (th >> 3)) & 7;
    const int irot = (ij + rot * 8) & 63;
    r.u[e] = buf[th * 64 + irot];
  }
  return r.v;
}

__global__ __launch_bounds__(256) void attn_scores_mfma(
    const uint16_t* __restrict__ Qb, const uint16_t* __restrict__ Kb,
    float* __restrict__ attn) {
  const int n = blockIdx.x;
  __shared__ uint16_t q_l[2][4096];
  __shared__ uint16_t k_l[2][4096];
  __shared__ float scores_l[64 * 68];

  const int t = threadIdx.x;
  const int lane = t & 63;
  const int w = t >> 6;
  const int i0w = (w >> 1) * 32, j0w = (w & 1) * 32;

  const uint16_t* Qn = Qb + (size_t)n * 32768;
  const uint16_t* Kn = Kb + (size_t)n * 32768;

  const int g1 = t, g2 = t + 256;
  const int th1 = g1 >> 3, th2 = g2 >> 3;
  const int s1 = (((g1 & 7) - ((th1 + 2 * (th1 >> 3)) & 7)) & 7);
  const int s2 = (((g2 & 7) - ((th2 + 2 * (th2 >> 3)) & 7)) & 7);
  const size_t so1 = (size_t)th1 * 64 + s1 * 8;
  const size_t so2 = (size_t)th2 * 64 + s2 * 8;

#define STAGE_CH(bf, cm)                                                    \
  do {                                                                      \
    const size_t co_ = (size_t)(cm) * 4096;                                 \
    GLOAD_LDS16(Qn + co_ + so1, (char*)&q_l[bf][0] + g1 * 16);              \
    GLOAD_LDS16(Qn + co_ + so2, (char*)&q_l[bf][0] + g2 * 16);              \
    GLOAD_LDS16(Kn + co_ + so1, (char*)&k_l[bf][0] + g1 * 16);              \
    GLOAD_LDS16(Kn + co_ + so2, (char*)&k_l[bf][0] + g2 * 16);              \
  } while (0)

  f32x4 acc[2][2] = {};

  STAGE_CH(0, 0);
  asm volatile("s_waitcnt vmcnt(0)" ::: "memory");
  __syncthreads();

  for (int cm = 0; cm < 8; ++cm) {
    const int bf = cm & 1;
    if (cm < 7) STAGE_CH(bf ^ 1, cm + 1);
#pragma unroll
    for (int ks = 0; ks < 2; ++ks) {
      const int thb = ks * 32 + (lane >> 4) * 8;
      bf16x8 aa0 = load_frag_rot(&q_l[bf][0], i0w + (lane & 15), thb);
      bf16x8 aa1 = load_frag_rot(&q_l[bf][0], i0w + 16 + (lane & 15), thb);
      bf16x8 bb0 = load_frag_rot(&k_l[bf][0], j0w + (lane & 15), thb);
      bf16x8 bb1 = load_frag_rot(&k_l[bf][0], j0w + 16 + (lane & 15), thb);
      acc[0][0] = __builtin_amdgcn_mfma_f32_16x16x32_bf16(aa0, bb0, acc[0][0], 0, 0, 0);
      acc[0][1] = __builtin_amdgcn_mfma_f32_16x16x32_bf16(aa0, bb1, acc[0][1], 0, 0, 0);
      acc[1][0] = __builtin_amdgcn_mfma_f32_16x16x32_bf16(aa1, bb0, acc[1][0], 0, 0, 0);
      acc[1][1] = __builtin_amdgcn_mfma_f32_16x16x32_bf16(aa1, bb1, acc[1][1], 0, 0, 0);
    }
    asm volatile("s_waitcnt vmcnt(0)" ::: "memory");
    __syncthreads();
  }
#undef STAGE_CH

#pragma unroll
  for (int fi = 0; fi < 2; ++fi)
#pragma unroll
    for (int fj = 0; fj < 2; ++fj)
#pragma unroll
      for (int jr = 0; jr < 4; ++jr) {
        const int i = i0w + fi * 16 + (lane >> 4) * 4 + jr;
        const int j = j0w + fj * 16 + (lane & 15);
        scores_l[i * 68 + j] = acc[fi][fj][jr];
      }
  __syncthreads();

  {
    const int i = t >> 2, jg = t & 3;
    float pv[16];
    *(float4*)(pv + 0)  = *(const float4*)&scores_l[i * 68 + jg * 16 + 0];
    *(float4*)(pv + 4)  = *(const float4*)&scores_l[i * 68 + jg * 16 + 4];
    *(float4*)(pv + 8)  = *(const float4*)&scores_l[i * 68 + jg * 16 + 8];
    *(float4*)(pv + 12) = *(const float4*)&scores_l[i * 68 + jg * 16 + 12];
    float m = pv[0];
#pragma unroll
    for (int q = 1; q < 16; ++q) m = fmaxf(m, pv[q]);
    m = fmaxf(m, __shfl_xor(m, 1, 64));
    m = fmaxf(m, __shfl_xor(m, 2, 64));
    const float sc = 0.044194173824159216f * 1.4426950408889634f;
    float e[16];
    float ssum = 0.f;
#pragma unroll
    for (int q = 0; q < 16; ++q) {
      e[q] = exp2f((pv[q] - m) * sc);
      ssum += e[q];
    }
    ssum += __shfl_xor(ssum, 1, 64);
    ssum += __shfl_xor(ssum, 2, 64);
    const float inv = 1.0f / ssum;
    float ov[16];
#pragma unroll
    for (int q = 0; q < 16; ++q) ov[q] = e[q] * inv;
    float* dst = attn + (size_t)n * 4096 + i * 64 + jg * 16;
    *(float4*)(dst + 0)  = *(float4*)(ov + 0);
    *(float4*)(dst + 4)  = *(float4*)(ov + 4);
    *(float4*)(dst + 8)  = *(float4*)(ov + 8);
    *(float4*)(dst + 12) = *(float4*)(ov + 12);
  }
}

// ---------------- V = x-slab * Wv^T ; context = V @ attn ; leaky; scatter ----
__global__ __launch_bounds__(256) void ctx_kernel(
    const float* __restrict__ x, const float* __restrict__ Wv,
    const float* __restrict__ attn, float* __restrict__ out) {
  const int n = blockIdx.x >> 3, ut = blockIdx.x & 7;
  const int b = n >> 3, g = n & 7;
  const int u0 = ut * 64;
  __shared__ float attn_l[64 * 64];
  __shared__ float wv_l[64 * 64];
  __shared__ float x_l[64 * 64];
  __shared__ float v_l[64 * 64];
  const int t = threadIdx.x;

#pragma unroll
  for (int r = 0; r < 4; ++r) {
    ((float4*)attn_l)[r * 256 + t] =
        ((const float4*)(attn + (size_t)n * 4096))[r * 256 + t];
    ((float4*)wv_l)[r * 256 + t] = ((const float4*)Wv)[r * 256 + t];
  }
  {
    const float* xbase = x + (size_t)b * 262144 + (size_t)g * 512 + u0;
    const int ul4 = (t & 15) * 4;
    const int cc0 = t >> 4;
#pragma unroll
    for (int r = 0; r < 4; ++r) {
      int cc = cc0 + r * 16;
      *(float4*)&x_l[cc * 64 + ul4] = *(const float4*)&xbase[(size_t)cc * 4096 + ul4];
    }
  }
  __syncthreads();
  {
    const int ul = t & 63, e0 = t >> 6;
    float vacc[16];
#pragma unroll
    for (int ee = 0; ee < 16; ++ee) vacc[ee] = 0.f;
    for (int cc = 0; cc < 64; ++cc) {
      float xv = x_l[cc * 64 + ul];
#pragma unroll
      for (int ee = 0; ee < 16; ++ee)
        vacc[ee] += xv * wv_l[(e0 + 4 * ee) * 64 + cc];
    }
#pragma unroll
    for (int ee = 0; ee < 16; ++ee) v_l[(e0 + 4 * ee) * 64 + ul] = vacc[ee];
  }
  __syncthreads();
  {
    const int ul = t & 63, j0 = t >> 6;
    float cacc[16];
#pragma unroll
    for (int jj = 0; jj < 16; ++jj) cacc[jj] = 0.f;
    for (int c = 0; c < 64; ++c) {
      float vv = v_l[c * 64 + ul];
#pragma unroll
      for (int jj = 0; jj < 16; ++jj)
        cacc[jj] += vv * attn_l[c * 64 + j0 + 4 * jj];
    }
    float* ob = out + (size_t)b * 262144 + (size_t)g * 8 * 4096;
#pragma unroll
    for (int jj = 0; jj < 16; ++jj) {
      int j = j0 + 4 * jj;
      float v = cacc[jj];
      v = v > 0.f ? v : 0.2f * v;
      ob[(size_t)(j >> 3) * 4096 + (size_t)(j & 7) * 512 + u0 + ul] = v;
    }
  }
}

extern "C" void kernel_launch(void* const* d_in, const int* in_sizes, int n_in,
                              void* d_out, int out_size, void* d_ws, size_t ws_size,
                              hipStream_t stream) {
  const float* z  = (const float*)d_in[0];
  const float* x  = (const float*)d_in[1];
  const float* Wq = (const float*)d_in[2];
  const float* Wk = (const float*)d_in[3];
  const float* Wv = (const float*)d_in[4];
  float* out = (float*)d_out;

  char* ws = (char*)d_ws;
  uint16_t* zb   = (uint16_t*)(ws);                  // 16 MB bf16 z
  uint16_t* qbo  = (uint16_t*)(ws + 16777216);       // 16 MB bf16 Q
  uint16_t* kbo  = (uint16_t*)(ws + 33554432);       // 16 MB bf16 K
  float*    attn = (float*)(ws + 50331648);          // 4 MB f32

  cvt_z<<<4096, 256, 0, stream>>>(z, zb);

  (void)hipFuncSetAttribute((const void*)gemm_qk16,
                            hipFuncAttributeMaxDynamicSharedMemorySize, 131072);
  gemm_qk16<<<256, 1024, 131072, stream>>>(zb, Wq, Wk, qbo, kbo);

  attn_scores_mfma<<<256, 256, 0, stream>>>(qbo, kbo, attn);
  ctx_kernel<<<2048, 256, 0, stream>>>(x, Wv, attn, out);
}

// Round 13
// 229.489 us; speedup vs baseline: 1.6178x; 1.5708x over previous
//
#include <hip/hip_runtime.h>
#include <hip/hip_bf16.h>
#include <stdint.h>

typedef __attribute__((ext_vector_type(8))) __bf16 bf16x8;
typedef __attribute__((ext_vector_type(4))) float f32x4;

#define GLOAD_LDS16(gp, lp) __builtin_amdgcn_global_load_lds( \
    (const __attribute__((address_space(1))) void*)(gp),      \
    (__attribute__((address_space(3))) void*)(lp), 16, 0, 0)

__device__ __forceinline__ uint16_t f2bf_rne(float f) {
  uint32_t u = __float_as_uint(f);
  u += 0x7FFFu + ((u >> 16) & 1u);
  return (uint16_t)(u >> 16);
}

// ---------------- f32 -> bf16 conversion for z only (48 MB traffic) ---------
__global__ __launch_bounds__(256) void cvt_z(
    const float* __restrict__ src, uint16_t* __restrict__ dst) {
  int i = blockIdx.x * 256 + threadIdx.x;
  const float4* s4 = (const float4*)src;
  float4 a = s4[2 * i], b = s4[2 * i + 1];
  union { uint16_t u[8]; uint4 v; } o;
  o.u[0] = f2bf_rne(a.x); o.u[1] = f2bf_rne(a.y);
  o.u[2] = f2bf_rne(a.z); o.u[3] = f2bf_rne(a.w);
  o.u[4] = f2bf_rne(b.x); o.u[5] = f2bf_rne(b.y);
  o.u[6] = f2bf_rne(b.z); o.u[7] = f2bf_rne(b.w);
  ((uint4*)dst)[i] = o.v;
}

// ---------------- bf16 GEMM, 256x256 tile, 8 waves, ring-4 BK=32 ------------
// R13: W-cvt fused into B staging (f32->reg->pack->swizzled ds_write), run at
// 512 threads so the register cost FITS: R10-R12's regression was spill —
// 1024-thr blocks pin the budget at 128 unified regs (4 waves/SIMD minimum)
// and R6 already used exactly 128 (acc 64 AGPR + 64 VGPR). At 512 thr /
// 2 waves/SIMD the budget is 256: acc[8][4]=128 + frags 48 + 3 B-bufs 48 +
// addr ~20 = ~244. Ledger (R11-verified): iter j: ds_reads slot j&3;
// load B(j+3)->buf(j%3) (4 f32x4) + gload A(j+3) (2 ops); MFMA x32;
// vmcnt(12) => all <= j-2 drained (B(j+1) regs, A(j+1) LDS; 2-iter slack);
// pack B(j+1)->slot (j+1)&3 (last read iter j-3); lgkmcnt(0); barrier.
#define PH_BAR() do { asm volatile("" ::: "memory");            \
                      __builtin_amdgcn_s_barrier();             \
                      asm volatile("" ::: "memory"); } while (0)

#define PACK_B(KT, PB)                                                         \
  do {                                                                         \
    uint4 w0_, w1_;                                                            \
    w0_.x = (uint32_t)f2bf_rne(PB[0][0]) | ((uint32_t)f2bf_rne(PB[0][1]) << 16); \
    w0_.y = (uint32_t)f2bf_rne(PB[0][2]) | ((uint32_t)f2bf_rne(PB[0][3]) << 16); \
    w0_.z = (uint32_t)f2bf_rne(PB[1][0]) | ((uint32_t)f2bf_rne(PB[1][1]) << 16); \
    w0_.w = (uint32_t)f2bf_rne(PB[1][2]) | ((uint32_t)f2bf_rne(PB[1][3]) << 16); \
    w1_.x = (uint32_t)f2bf_rne(PB[2][0]) | ((uint32_t)f2bf_rne(PB[2][1]) << 16); \
    w1_.y = (uint32_t)f2bf_rne(PB[2][2]) | ((uint32_t)f2bf_rne(PB[2][3]) << 16); \
    w1_.z = (uint32_t)f2bf_rne(PB[3][0]) | ((uint32_t)f2bf_rne(PB[3][1]) << 16); \
    w1_.w = (uint32_t)f2bf_rne(PB[3][2]) | ((uint32_t)f2bf_rne(PB[3][3]) << 16); \
    char* Bd_ = lds + (((KT) + 1) & 3) * 32768 + 16384;                        \
    *(uint4*)(Bd_ + bw0) = w0_;                                                \
    *(uint4*)(Bd_ + bw1) = w1_;                                                \
  } while (0)

#define STEP(KT, PB, LB, DO_LD, DO_PK, VMN)                                    \
  do {                                                                         \
    const char* Sb_ = lds + ((KT) & 3) * 32768;                                \
    bf16x8 aa[8], bb[4];                                                       \
    _Pragma("unroll")                                                          \
    for (int n_ = 0; n_ < 4; ++n_)                                             \
      bb[n_] = *(const bf16x8*)(Sb_ + 16384 + boff + n_ * 1024);               \
    _Pragma("unroll")                                                          \
    for (int m_ = 0; m_ < 8; ++m_)                                             \
      aa[m_] = *(const bf16x8*)(Sb_ + aoff + m_ * 1024);                       \
    if (DO_LD) {                                                               \
      _Pragma("unroll")                                                        \
      for (int q_ = 0; q_ < 4; ++q_)                                           \
        LB[q_] = *(const f32x4*)(bsrc + (size_t)((KT) + 3) * 32 + q_ * 4);     \
      GLOAD_LDS16(aptr  + (size_t)((KT) + 3) * 32,                             \
                  lds + (((KT) + 3) & 3) * 32768 + t16);                       \
      GLOAD_LDS16(aptr2 + (size_t)((KT) + 3) * 32,                             \
                  lds + (((KT) + 3) & 3) * 32768 + 8192 + t16);                \
    }                                                                          \
    __builtin_amdgcn_s_setprio(1);                                             \
    _Pragma("unroll")                                                          \
    for (int m_ = 0; m_ < 8; ++m_)                                             \
      _Pragma("unroll")                                                        \
      for (int n_ = 0; n_ < 4; ++n_)                                           \
        acc[m_][n_] = __builtin_amdgcn_mfma_f32_16x16x32_bf16(                 \
            aa[m_], bb[n_], acc[m_][n_], 0, 0, 0);                             \
    __builtin_amdgcn_s_setprio(0);                                             \
    asm volatile("s_waitcnt vmcnt(" #VMN ")" ::: "memory");                    \
    if (DO_PK) PACK_B(KT, PB);                                                 \
    asm volatile("s_waitcnt lgkmcnt(0)" ::: "memory");                         \
    PH_BAR();                                                                  \
  } while (0)

__global__ __launch_bounds__(512, 2) void gemm_qk8wf(
    const uint16_t* __restrict__ A,
    const float* __restrict__ Wq, const float* __restrict__ Wk,
    uint16_t* __restrict__ Cq, uint16_t* __restrict__ Ck) {
  extern __shared__ char lds[];  // 131072: 4 ring slots x (A 16K + B 16K)

  // bijective supertile: xcd = gid&7 -> (tm half, tn quarter); 32 blocks/XCD
  const int gid = blockIdx.x;
  const int xcd = gid & 7;
  const int idx = gid >> 3;          // 0..31
  const int which = idx & 1;
  const int r = idx >> 1;            // 0..15
  const int tm = (xcd & 1) * 4 + (r & 3);
  const int tn = (xcd >> 1) * 4 + (r >> 2);

  const float* Bmat = which ? Wk : Wq;
  uint16_t* C = which ? Ck : Cq;
  const int m0 = tm * 256, n0 = tn * 256;

  const int t = threadIdx.x;
  const int lane = t & 63;
  const int w = t >> 6;              // 0..7
  const int wm = w >> 2, wn = w & 3; // 2x4 wave grid, each 128x64 output
  const int t16 = t * 16;

  // A staging (gload_lds): thread t covers rows t>>2 and t>>2+128,
  // k-granule t&3, pre-swizzled source (involution with read-side sl)
  const int gsw = (((t & 3) ^ ((t >> 3) & 3)) * 8);
  const uint16_t* aptr  = A + (size_t)(m0 + (t >> 2)) * 4096 + gsw;
  const uint16_t* aptr2 = aptr + (size_t)128 * 4096;

  // B staging (f32 reg + cvt + swizzled ds_write): thread covers row t>>1,
  // k-half t&1 (16 f32 = granules 2h, 2h+1); write granule g -> g^((r>>1)&3)
  const float* bsrc = Bmat + (size_t)(n0 + (t >> 1)) * 4096 + (t & 1) * 16;
  {
  }
  const int br_ = t >> 1, bh_ = t & 1, bs_ = (br_ >> 1) & 3;
  const int bw0 = br_ * 64 + ((2 * bh_) ^ bs_) * 16;
  const int bw1 = br_ * 64 + ((2 * bh_ + 1) ^ bs_) * 16;

  // ds_read byte offsets (XOR involution on the read side)
  const int sl = ((lane >> 4) ^ ((lane & 15) >> 1)) & 3;
  const int aoff = (wm * 128 + (lane & 15)) * 64 + sl * 16;
  const int boff = (wn * 64 + (lane & 15)) * 64 + sl * 16;

  f32x4 acc[8][4] = {};
  f32x4 b0[4], b1[4], b2[4];  // 3 B f32 buffers (rotation: B(j+3)->buf(j%3))

  // prologue: A tiles 0,1,2 -> slots; B tiles 0,1,2 -> buf0,1,2; drain all;
  // pack B0 -> slot 0.
#pragma unroll
  for (int p = 0; p < 3; ++p) {
    GLOAD_LDS16(aptr  + (size_t)p * 32, lds + p * 32768 + t16);
    GLOAD_LDS16(aptr2 + (size_t)p * 32, lds + p * 32768 + 8192 + t16);
  }
#pragma unroll
  for (int q_ = 0; q_ < 4; ++q_) {
    b0[q_] = *(const f32x4*)(bsrc + q_ * 4);
    b1[q_] = *(const f32x4*)(bsrc + 32 + q_ * 4);
    b2[q_] = *(const f32x4*)(bsrc + 64 + q_ * 4);
  }
  asm volatile("s_waitcnt vmcnt(0)" ::: "memory");
  PACK_B(-1, b0);  // (KT+1)&3 = 0 -> slot 0
  asm volatile("s_waitcnt lgkmcnt(0)" ::: "memory");
  PH_BAR();

  // main: j = 0..122 in 41 triples; pack B(j+1)=buf((j+1)%3), load->buf(j%3)
  for (int it = 0; it < 41; ++it) {
    const int kt0 = it * 3;
    STEP(kt0 + 0, b1, b0, 1, 1, 12);
    STEP(kt0 + 1, b2, b1, 1, 1, 12);
    STEP(kt0 + 2, b0, b2, 1, 1, 12);
  }
  // tail
  STEP(123, b1, b0, 1, 1, 12);  // loads B126->b0, A126; packs B124
  STEP(124, b2, b1, 1, 1, 12);  // loads B127->b1, A127; packs B125
  STEP(125, b0, b2, 0, 1, 6);   // packs B126 (loaded iter 123)
  STEP(126, b1, b2, 0, 1, 0);   // packs B127 (loaded iter 124)
  {  // j = 127: pure compute
    const char* Sb_ = lds + 3 * 32768;
    bf16x8 aa[8], bb[4];
#pragma unroll
    for (int n_ = 0; n_ < 4; ++n_)
      bb[n_] = *(const bf16x8*)(Sb_ + 16384 + boff + n_ * 1024);
#pragma unroll
    for (int m_ = 0; m_ < 8; ++m_)
      aa[m_] = *(const bf16x8*)(Sb_ + aoff + m_ * 1024);
#pragma unroll
    for (int m_ = 0; m_ < 8; ++m_)
#pragma unroll
      for (int n_ = 0; n_ < 4; ++n_)
        acc[m_][n_] = __builtin_amdgcn_mfma_f32_16x16x32_bf16(
            aa[m_], bb[n_], acc[m_][n_], 0, 0, 0);
  }

  // epilogue: C/D layout col=lane&15, row=(lane>>4)*4+j ; store bf16
  const int colb = n0 + wn * 64 + (lane & 15);
  const int rowb = m0 + wm * 128 + (lane >> 4) * 4;
#pragma unroll
  for (int m_ = 0; m_ < 8; ++m_)
#pragma unroll
    for (int n_ = 0; n_ < 4; ++n_)
#pragma unroll
      for (int j = 0; j < 4; ++j)
        C[(size_t)(rowb + m_ * 16 + j) * 4096 + colb + n_ * 16] =
            f2bf_rne(acc[m_][n_][j]);
}

// ---------------- MFMA scores + softmax -> attn[256][64][64] f32 ------------
__device__ __forceinline__ bf16x8 load_frag_rot(const uint16_t* buf,
                                                int ij, int thb) {
  union { uint16_t u[8]; bf16x8 v; } r;
#pragma unroll
  for (int e = 0; e < 8; ++e) {
    const int th = thb + e;
    const int rot = (th + 2 * (th >> 3)) & 7;
    const int irot = (ij + rot * 8) & 63;
    r.u[e] = buf[th * 64 + irot];
  }
  return r.v;
}

__global__ __launch_bounds__(256) void attn_scores_mfma(
    const uint16_t* __restrict__ Qb, const uint16_t* __restrict__ Kb,
    float* __restrict__ attn) {
  const int n = blockIdx.x;
  __shared__ uint16_t q_l[2][4096];
  __shared__ uint16_t k_l[2][4096];
  __shared__ float scores_l[64 * 68];

  const int t = threadIdx.x;
  const int lane = t & 63;
  const int w = t >> 6;
  const int i0w = (w >> 1) * 32, j0w = (w & 1) * 32;

  const uint16_t* Qn = Qb + (size_t)n * 32768;
  const uint16_t* Kn = Kb + (size_t)n * 32768;

  const int g1 = t, g2 = t + 256;
  const int th1 = g1 >> 3, th2 = g2 >> 3;
  const int s1 = (((g1 & 7) - ((th1 + 2 * (th1 >> 3)) & 7)) & 7);
  const int s2 = (((g2 & 7) - ((th2 + 2 * (th2 >> 3)) & 7)) & 7);
  const size_t so1 = (size_t)th1 * 64 + s1 * 8;
  const size_t so2 = (size_t)th2 * 64 + s2 * 8;

#define STAGE_CH(bf, cm)                                                    \
  do {                                                                      \
    const size_t co_ = (size_t)(cm) * 4096;                                 \
    GLOAD_LDS16(Qn + co_ + so1, (char*)&q_l[bf][0] + g1 * 16);              \
    GLOAD_LDS16(Qn + co_ + so2, (char*)&q_l[bf][0] + g2 * 16);              \
    GLOAD_LDS16(Kn + co_ + so1, (char*)&k_l[bf][0] + g1 * 16);              \
    GLOAD_LDS16(Kn + co_ + so2, (char*)&k_l[bf][0] + g2 * 16);              \
  } while (0)

  f32x4 acc[2][2] = {};

  STAGE_CH(0, 0);
  asm volatile("s_waitcnt vmcnt(0)" ::: "memory");
  __syncthreads();

  for (int cm = 0; cm < 8; ++cm) {
    const int bf = cm & 1;
    if (cm < 7) STAGE_CH(bf ^ 1, cm + 1);
#pragma unroll
    for (int ks = 0; ks < 2; ++ks) {
      const int thb = ks * 32 + (lane >> 4) * 8;
      bf16x8 aa0 = load_frag_rot(&q_l[bf][0], i0w + (lane & 15), thb);
      bf16x8 aa1 = load_frag_rot(&q_l[bf][0], i0w + 16 + (lane & 15), thb);
      bf16x8 bb0 = load_frag_rot(&k_l[bf][0], j0w + (lane & 15), thb);
      bf16x8 bb1 = load_frag_rot(&k_l[bf][0], j0w + 16 + (lane & 15), thb);
      acc[0][0] = __builtin_amdgcn_mfma_f32_16x16x32_bf16(aa0, bb0, acc[0][0], 0, 0, 0);
      acc[0][1] = __builtin_amdgcn_mfma_f32_16x16x32_bf16(aa0, bb1, acc[0][1], 0, 0, 0);
      acc[1][0] = __builtin_amdgcn_mfma_f32_16x16x32_bf16(aa1, bb0, acc[1][0], 0, 0, 0);
      acc[1][1] = __builtin_amdgcn_mfma_f32_16x16x32_bf16(aa1, bb1, acc[1][1], 0, 0, 0);
    }
    asm volatile("s_waitcnt vmcnt(0)" ::: "memory");
    __syncthreads();
  }
#undef STAGE_CH

#pragma unroll
  for (int fi = 0; fi < 2; ++fi)
#pragma unroll
    for (int fj = 0; fj < 2; ++fj)
#pragma unroll
      for (int jr = 0; jr < 4; ++jr) {
        const int i = i0w + fi * 16 + (lane >> 4) * 4 + jr;
        const int j = j0w + fj * 16 + (lane & 15);
        scores_l[i * 68 + j] = acc[fi][fj][jr];
      }
  __syncthreads();

  {
    const int i = t >> 2, jg = t & 3;
    float pv[16];
    *(float4*)(pv + 0)  = *(const float4*)&scores_l[i * 68 + jg * 16 + 0];
    *(float4*)(pv + 4)  = *(const float4*)&scores_l[i * 68 + jg * 16 + 4];
    *(float4*)(pv + 8)  = *(const float4*)&scores_l[i * 68 + jg * 16 + 8];
    *(float4*)(pv + 12) = *(const float4*)&scores_l[i * 68 + jg * 16 + 12];
    float m = pv[0];
#pragma unroll
    for (int q = 1; q < 16; ++q) m = fmaxf(m, pv[q]);
    m = fmaxf(m, __shfl_xor(m, 1, 64));
    m = fmaxf(m, __shfl_xor(m, 2, 64));
    const float sc = 0.044194173824159216f * 1.4426950408889634f;
    float e[16];
    float ssum = 0.f;
#pragma unroll
    for (int q = 0; q < 16; ++q) {
      e[q] = exp2f((pv[q] - m) * sc);
      ssum += e[q];
    }
    ssum += __shfl_xor(ssum, 1, 64);
    ssum += __shfl_xor(ssum, 2, 64);
    const float inv = 1.0f / ssum;
    float ov[16];
#pragma unroll
    for (int q = 0; q < 16; ++q) ov[q] = e[q] * inv;
    float* dst = attn + (size_t)n * 4096 + i * 64 + jg * 16;
    *(float4*)(dst + 0)  = *(float4*)(ov + 0);
    *(float4*)(dst + 4)  = *(float4*)(ov + 4);
    *(float4*)(dst + 8)  = *(float4*)(ov + 8);
    *(float4*)(dst + 12) = *(float4*)(ov + 12);
  }
}

// ---------------- V = x-slab * Wv^T ; context = V @ attn ; leaky; scatter ----
__global__ __launch_bounds__(256) void ctx_kernel(
    const float* __restrict__ x, const float* __restrict__ Wv,
    const float* __restrict__ attn, float* __restrict__ out) {
  const int n = blockIdx.x >> 3, ut = blockIdx.x & 7;
  const int b = n >> 3, g = n & 7;
  const int u0 = ut * 64;
  __shared__ float attn_l[64 * 64];
  __shared__ float wv_l[64 * 64];
  __shared__ float x_l[64 * 64];
  __shared__ float v_l[64 * 64];
  const int t = threadIdx.x;

#pragma unroll
  for (int r = 0; r < 4; ++r) {
    ((float4*)attn_l)[r * 256 + t] =
        ((const float4*)(attn + (size_t)n * 4096))[r * 256 + t];
    ((float4*)wv_l)[r * 256 + t] = ((const float4*)Wv)[r * 256 + t];
  }
  {
    const float* xbase = x + (size_t)b * 262144 + (size_t)g * 512 + u0;
    const int ul4 = (t & 15) * 4;
    const int cc0 = t >> 4;
#pragma unroll
    for (int r = 0; r < 4; ++r) {
      int cc = cc0 + r * 16;
      *(float4*)&x_l[cc * 64 + ul4] = *(const float4*)&xbase[(size_t)cc * 4096 + ul4];
    }
  }
  __syncthreads();
  {
    const int ul = t & 63, e0 = t >> 6;
    float vacc[16];
#pragma unroll
    for (int ee = 0; ee < 16; ++ee) vacc[ee] = 0.f;
    for (int cc = 0; cc < 64; ++cc) {
      float xv = x_l[cc * 64 + ul];
#pragma unroll
      for (int ee = 0; ee < 16; ++ee)
        vacc[ee] += xv * wv_l[(e0 + 4 * ee) * 64 + cc];
    }
#pragma unroll
    for (int ee = 0; ee < 16; ++ee) v_l[(e0 + 4 * ee) * 64 + ul] = vacc[ee];
  }
  __syncthreads();
  {
    const int ul = t & 63, j0 = t >> 6;
    float cacc[16];
#pragma unroll
    for (int jj = 0; jj < 16; ++jj) cacc[jj] = 0.f;
    for (int c = 0; c < 64; ++c) {
      float vv = v_l[c * 64 + ul];
#pragma unroll
      for (int jj = 0; jj < 16; ++jj)
        cacc[jj] += vv * attn_l[c * 64 + j0 + 4 * jj];
    }
    float* ob = out + (size_t)b * 262144 + (size_t)g * 8 * 4096;
#pragma unroll
    for (int jj = 0; jj < 16; ++jj) {
      int j = j0 + 4 * jj;
      float v = cacc[jj];
      v = v > 0.f ? v : 0.2f * v;
      ob[(size_t)(j >> 3) * 4096 + (size_t)(j & 7) * 512 + u0 + ul] = v;
    }
  }
}

extern "C" void kernel_launch(void* const* d_in, const int* in_sizes, int n_in,
                              void* d_out, int out_size, void* d_ws, size_t ws_size,
                              hipStream_t stream) {
  const float* z  = (const float*)d_in[0];
  const float* x  = (const float*)d_in[1];
  const float* Wq = (const float*)d_in[2];
  const float* Wk = (const float*)d_in[3];
  const float* Wv = (const float*)d_in[4];
  float* out = (float*)d_out;

  char* ws = (char*)d_ws;
  uint16_t* zb   = (uint16_t*)(ws);                  // 16 MB bf16 z
  uint16_t* qbo  = (uint16_t*)(ws + 16777216);       // 16 MB bf16 Q
  uint16_t* kbo  = (uint16_t*)(ws + 33554432);       // 16 MB bf16 K
  float*    attn = (float*)(ws + 50331648);          // 4 MB f32

  cvt_z<<<4096, 256, 0, stream>>>(z, zb);

  (void)hipFuncSetAttribute((const void*)gemm_qk8wf,
                            hipFuncAttributeMaxDynamicSharedMemorySize, 131072);
  gemm_qk8wf<<<256, 512, 131072, stream>>>(zb, Wq, Wk, qbo, kbo);

  attn_scores_mfma<<<256, 256, 0, stream>>>(qbo, kbo, attn);
  ctx_kernel<<<2048, 256, 0, stream>>>(x, Wv, attn, out);
}